// Round 5
// baseline (326.162 us; speedup 1.0000x reference)
//
#include <hip/hip_runtime.h>

// Fused attention block: q/k/v = relu(X W + b); A = softmax(qk^T/sqrt(C)); out = relu((A v) FC + b)
// B=8, Lq=Lk=2048, C1=C=512.  All matmuls via bf16 16x16x32 MFMA, fp32 accumulate.
// R4->R5: (1) algebraic fusion out = relu(inv[m]*(P.(V.FC)) + b): FC pass + O traffic
// deleted, KV projections fused (N=1024); (2) PVF runs BK=128 (64KB LDS, 64 MFMA per
// barrier-pair on the K=2048 loop); (3) all epilogues single-pass through the main-loop
// LDS (XOR-chunked), 1 barrier-pair, 64B-coalesced stores.

typedef __attribute__((ext_vector_type(8))) short short8;  // 8 bf16 (4 VGPRs)
typedef __attribute__((ext_vector_type(4))) float f32x4;

#define SEQ 2048
#define CH 512
#define NB 8
#define MTOT (NB * SEQ)   // 16384

// async global->LDS, 16B/lane; LDS dest = wave-uniform base + lane*16 (m104/m108)
#define GLDS16(gp, lp)                                                                  \
  __builtin_amdgcn_global_load_lds((const __attribute__((address_space(1))) void*)(gp), \
                                   (__attribute__((address_space(3))) void*)(lp), 16, 0, 0)

__device__ __forceinline__ unsigned short f2bf(float f) {  // fp32 -> bf16 RNE
  unsigned u = __float_as_uint(f);
  u += 0x7fffu + ((u >> 16) & 1u);
  return (unsigned short)(u >> 16);
}

// ---------------- fp32 -> bf16 elementwise: rep (4096 blocks) then rep1 ----------------
__global__ void cvt_bf16_kernel(const float* __restrict__ in0, unsigned short* __restrict__ out0,
                                const float* __restrict__ in1, unsigned short* __restrict__ out1) {
  int blk = blockIdx.x;
  const float* in = (blk < 4096) ? in0 : in1;
  unsigned short* out = (blk < 4096) ? out0 : out1;
  blk &= 4095;
  long i = ((long)blk * 256 + threadIdx.x) * 8;
  float4 a = *(const float4*)(in + i);
  float4 b = *(const float4*)(in + i + 4);
  ushort4 o0, o1;
  o0.x = f2bf(a.x); o0.y = f2bf(a.y); o0.z = f2bf(a.z); o0.w = f2bf(a.w);
  o1.x = f2bf(b.x); o1.y = f2bf(b.y); o1.z = f2bf(b.z); o1.w = f2bf(b.w);
  *(ushort4*)(out + i) = o0;
  *(ushort4*)(out + i + 4) = o1;
}

// ---------------- W[k][n] fp32 -> Wt[n][k] bf16, 4 weights in one dispatch ----------------
// z=0: Wq, z=1: Wk, z=2: Wv, z=3: FC  -> Wt + z*512*512  (so WtK|WtV form [1024][512])
__global__ __launch_bounds__(256) void wtrans_kernel(const float* __restrict__ W0,
                                                     const float* __restrict__ W1,
                                                     const float* __restrict__ W2,
                                                     const float* __restrict__ W3,
                                                     unsigned short* __restrict__ Wt) {
  __shared__ __attribute__((aligned(16))) unsigned short tile[64 * 72];
  const int z = blockIdx.z;
  const float* W = (z == 0) ? W0 : (z == 1) ? W1 : (z == 2) ? W2 : W3;
  unsigned short* Wtz = Wt + (long)z * 512 * 512;
  const int t = threadIdx.x;
  const int k0 = blockIdx.y * 64, n0 = blockIdx.x * 64;
  const int r = t >> 4, cq = (t & 15) * 4;
#pragma unroll
  for (int j = 0; j < 4; ++j) {
    int row = r + 16 * j;  // k index
    float4 v = *(const float4*)&W[(long)(k0 + row) * 512 + n0 + cq];
    tile[row * 72 + cq + 0] = f2bf(v.x);
    tile[row * 72 + cq + 1] = f2bf(v.y);
    tile[row * 72 + cq + 2] = f2bf(v.z);
    tile[row * 72 + cq + 3] = f2bf(v.w);
  }
  __syncthreads();
#pragma unroll
  for (int j = 0; j < 4; ++j) {
    int row = r + 16 * j;  // n index
    ushort4 o;
    o.x = tile[(cq + 0) * 72 + row];
    o.y = tile[(cq + 1) * 72 + row];
    o.z = tile[(cq + 2) * 72 + row];
    o.w = tile[(cq + 3) * 72 + row];
    *(ushort4*)&Wtz[(long)(n0 + row) * 512 + k0 + cq] = o;
  }
}

// ---------------- X[b*2048+k][d] bf16 -> Xt[b][d][k] bf16 (used for VF) ----------------
__global__ __launch_bounds__(256) void vtrans_kernel(const unsigned short* __restrict__ V,
                                                     unsigned short* __restrict__ Vt) {
  __shared__ __attribute__((aligned(16))) unsigned short tile[64 * 72];
  const int t = threadIdx.x;
  const int b = blockIdx.z;
  const int kk0 = blockIdx.y * 64;  // seq
  const int d0 = blockIdx.x * 64;   // channel
  const unsigned short* Vb = V + (long)b * SEQ * CH;
  unsigned short* Vtb = Vt + (long)b * CH * SEQ;
  const int r = t >> 4, cq = (t & 15) * 4;
#pragma unroll
  for (int j = 0; j < 4; ++j) {
    int row = r + 16 * j;  // k index
    ushort4 v = *(const ushort4*)&Vb[(long)(kk0 + row) * CH + d0 + cq];
    tile[row * 72 + cq + 0] = v.x;
    tile[row * 72 + cq + 1] = v.y;
    tile[row * 72 + cq + 2] = v.z;
    tile[row * 72 + cq + 3] = v.w;
  }
  __syncthreads();
#pragma unroll
  for (int j = 0; j < 4; ++j) {
    int row = r + 16 * j;  // d index
    ushort4 o;
    o.x = tile[(cq + 0) * 72 + row];
    o.y = tile[(cq + 1) * 72 + row];
    o.z = tile[(cq + 2) * 72 + row];
    o.w = tile[(cq + 3) * 72 + row];
    *(ushort4*)&Vtb[(long)(d0 + row) * SEQ + kk0 + cq] = o;
  }
}

// ---------------- Generic batched NT GEMM, 128x128 tile, 4 waves, BK in {64,128} ----------
// out[m][n] = EPI(sum_k A[m][k] * Bt[n][k])
// EPI 1: relu(acc+bias[n]) -> bf16          (q / kv projections)
// EPI 6: acc               -> bf16          (VF = V.FC)
// EPI 2: exp2(acc*scale)   -> bf16 P, rowsum[m] += sum_n p   (QK^T)
// EPI 5: relu(acc*inv[m]+bias[n]) -> fp32   (PVF, fused divide+FC-bias+relu)
// Staging: global_load_lds dwordx4, source-XOR swizzle (chunk ^= row & (BK/8-1)) so
// frag ds_read_b128 is 2-way.  Epilogue: single pass through the 2*128*BK LDS,
// XOR-chunked patch, 64B-coalesced stores, one barrier-pair.
template <int EPI, int LDA, int LDB, int LDO, int K, int BK>
__global__ __launch_bounds__(256) void gemm_nt(const unsigned short* __restrict__ A, long sAb,
                                               const unsigned short* __restrict__ Bt, long sBb,
                                               const float* __restrict__ bias,
                                               float* __restrict__ rowsum, long sRb,
                                               void* __restrict__ outp, long sOb) {
  __shared__ __attribute__((aligned(16))) unsigned short smem[2 * 128 * BK];
  unsigned short* Al = smem;
  unsigned short* Bl = smem + 128 * BK;
  const int t = threadIdx.x;
  const int w = t >> 6, l = t & 63;
  const int wr = w >> 1, wc = w & 1;
  const int lr = l & 15, lg = l >> 4;
  const int bz = blockIdx.z;
  const long m0 = (long)blockIdx.y * 128, n0 = (long)blockIdx.x * 128;
  const int NC = BK / 8;      // 16B chunks per LDS row
  const int rl = l / NC, cc0 = l % NC;
  unsigned short* la = &Al[32 * w * BK];  // wave-uniform LDS bases
  unsigned short* lb = &Bl[32 * w * BK];
  const unsigned short* gaJ[(BK == 128) ? 4 : 1];
  const unsigned short* gbJ[(BK == 128) ? 4 : 1];
  if (BK == 64) {
    const int srow = 32 * w + rl;
    const int sxor = (cc0 ^ (rl & 7)) * 8;
    gaJ[0] = A + bz * sAb + (long)(m0 + srow) * LDA + sxor;
    gbJ[0] = Bt + bz * sBb + (long)(n0 + srow) * LDB + sxor;
  } else {
#pragma unroll
    for (int jm = 0; jm < 4; ++jm) {
      const int srow = 32 * w + 4 * jm + rl;
      const int sxor = (cc0 ^ ((4 * jm + rl) & 15)) * 8;
      gaJ[jm] = A + bz * sAb + (long)(m0 + srow) * LDA + sxor;
      gbJ[jm] = Bt + bz * sBb + (long)(n0 + srow) * LDB + sxor;
    }
  }

  f32x4 acc[4][4] = {};
  for (int k0 = 0; k0 < K; k0 += BK) {
    if (BK == 64) {
#pragma unroll
      for (int j = 0; j < 4; ++j) {
        GLDS16(gaJ[0] + (long)8 * j * LDA, la + j * 8 * 64);
        GLDS16(gbJ[0] + (long)8 * j * LDB, lb + j * 8 * 64);
      }
      gaJ[0] += BK; gbJ[0] += BK;
    } else {
#pragma unroll
      for (int jm = 0; jm < 4; ++jm) {
        GLDS16(gaJ[jm], la + jm * 4 * 128);
        GLDS16(gaJ[jm] + (long)16 * LDA, la + (16 + 4 * jm) * 128);
        GLDS16(gbJ[jm], lb + jm * 4 * 128);
        GLDS16(gbJ[jm] + (long)16 * LDB, lb + (16 + 4 * jm) * 128);
        gaJ[jm] += BK; gbJ[jm] += BK;
      }
    }
    __syncthreads();
#pragma unroll
    for (int h = 0; h < BK / 32; ++h) {
      short8 af[4], bfr[4];
#pragma unroll
      for (int i = 0; i < 4; ++i) {
        const int kc = ((h * 4 + lg) ^ (lr & (NC - 1))) * 8;
        af[i]  = *(short8*)&Al[(64 * wr + 16 * i + lr) * BK + kc];
        bfr[i] = *(short8*)&Bl[(64 * wc + 16 * i + lr) * BK + kc];
      }
#pragma unroll
      for (int mi = 0; mi < 4; ++mi)
#pragma unroll
        for (int ni = 0; ni < 4; ++ni)
          acc[mi][ni] =
              __builtin_amdgcn_mfma_f32_16x16x32_bf16(af[mi], bfr[ni], acc[mi][ni], 0, 0, 0);
    }
    __syncthreads();
  }

  if (EPI == 1 || EPI == 6 || EPI == 2) {
    // bf16 single-pass epilogue via [128][128] XOR-chunked patch (32KB = whole smem @BK=64)
    unsigned short* patch = smem;
    float bv[4];
    if (EPI == 1) {
#pragma unroll
      for (int ni = 0; ni < 4; ++ni) bv[ni] = bias[n0 + 64 * wc + 16 * ni + lr];
    }
    float rsum[4][4] = {};
#pragma unroll
    for (int mi = 0; mi < 4; ++mi)
#pragma unroll
      for (int ni = 0; ni < 4; ++ni)
#pragma unroll
        for (int r = 0; r < 4; ++r) {
          const int m = 64 * wr + 16 * mi + 4 * lg + r;
          const int n = 64 * wc + 16 * ni + lr;
          float a = acc[mi][ni][r];
          unsigned short ob;
          if (EPI == 1)      ob = f2bf(fmaxf(a + bv[ni], 0.0f));
          else if (EPI == 6) ob = f2bf(a);
          else {
            float p = exp2f(a * 0.06375872f);  // (1/sqrt(512))*log2(e)
            ob = f2bf(p);
            rsum[mi][r] += __uint_as_float((unsigned)ob << 16);  // sum what PVF will see
          }
          patch[m * 128 + ((n >> 3) ^ (m & 15)) * 8 + (n & 7)] = ob;
        }
    __syncthreads();
    unsigned short* O = (unsigned short*)outp + bz * sOb;
    const int q = t & 3;
#pragma unroll
    for (int p = 0; p < 2; ++p) {
      const int m = 64 * p + (t >> 2);
#pragma unroll
      for (int i = 0; i < 4; ++i) {
        const int cc = i * 4 + q;  // 4 consecutive lanes -> 64B line
        short8 x = *(short8*)&patch[m * 128 + ((cc ^ (m & 15)) * 8)];
        *(short8*)&O[(m0 + m) * LDO + n0 + cc * 8] = x;
      }
    }
    if (EPI == 2) {
      float* rsw = rowsum + bz * sRb;
#pragma unroll
      for (int off = 1; off < 16; off <<= 1)
#pragma unroll
        for (int mi = 0; mi < 4; ++mi)
#pragma unroll
          for (int r = 0; r < 4; ++r) rsum[mi][r] += __shfl_xor(rsum[mi][r], off);
      if (lr == 0) {
#pragma unroll
        for (int mi = 0; mi < 4; ++mi)
#pragma unroll
          for (int r = 0; r < 4; ++r)
            atomicAdd(&rsw[m0 + 64 * wr + 16 * mi + 4 * lg + r], rsum[mi][r]);
      }
    }
  } else {  // EPI == 5 (BK=128): fp32 out via [128][128] f32 XOR-chunked patch (64KB)
    float* patchF = (float*)smem;
    float bv[4];
#pragma unroll
    for (int ni = 0; ni < 4; ++ni) bv[ni] = bias[n0 + 64 * wc + 16 * ni + lr];
    const float* rs = rowsum + bz * sRb;
    float inv[4][4];
#pragma unroll
    for (int mi = 0; mi < 4; ++mi)
#pragma unroll
      for (int r = 0; r < 4; ++r)
        inv[mi][r] = 1.0f / rs[m0 + 64 * wr + 16 * mi + 4 * lg + r];
#pragma unroll
    for (int mi = 0; mi < 4; ++mi)
#pragma unroll
      for (int ni = 0; ni < 4; ++ni)
#pragma unroll
        for (int r = 0; r < 4; ++r) {
          const int m = 64 * wr + 16 * mi + 4 * lg + r;
          const int n = 64 * wc + 16 * ni + lr;
          patchF[m * 128 + ((n >> 2) ^ (m & 31)) * 4 + (n & 3)] =
              fmaxf(acc[mi][ni][r] * inv[mi][r] + bv[ni], 0.0f);
        }
    __syncthreads();
    float* O = (float*)outp + bz * sOb;
    const int q = t & 3;
#pragma unroll
    for (int p = 0; p < 2; ++p) {
      const int m = 64 * p + (t >> 2);
#pragma unroll
      for (int i = 0; i < 8; ++i) {
        const int cc = i * 4 + q;  // 4 consecutive lanes -> 64B line
        f32x4 x = *(f32x4*)&patchF[m * 128 + ((cc ^ (m & 31)) * 4)];
        *(f32x4*)&O[(m0 + m) * LDO + n0 + cc * 4] = x;
      }
    }
  }
}

extern "C" void kernel_launch(void* const* d_in, const int* in_sizes, int n_in,
                              void* d_out, int out_size, void* d_ws, size_t ws_size,
                              hipStream_t stream) {
  const float* rep  = (const float*)d_in[0];
  const float* rep1 = (const float*)d_in[1];
  const float* Wq_w = (const float*)d_in[2];
  const float* Wq_b = (const float*)d_in[3];
  const float* Wk_w = (const float*)d_in[4];
  const float* Wk_b = (const float*)d_in[5];
  const float* Wv_w = (const float*)d_in[6];
  const float* Wv_b = (const float*)d_in[7];
  const float* FC_w = (const float*)d_in[8];
  const float* FC_b = (const float*)d_in[9];
  float* out = (float*)d_out;
  char* ws = (char*)d_ws;

  const size_t MB = 1024 * 1024;
  // layout: Qb 16MB | KVb 32MB | repb 16MB (->VFn) | rep1b 16MB (->VFt) | Wt 2MB |
  //         biasKV 8KB | Pbuf 64MB | rowsum 64KB
  unsigned short* Qb     = (unsigned short*)(ws + 0 * MB);
  unsigned short* KVb    = (unsigned short*)(ws + 16 * MB);
  unsigned short* repb   = (unsigned short*)(ws + 48 * MB);   // dead after Qproj -> VFn
  unsigned short* rep1b  = (unsigned short*)(ws + 64 * MB);   // dead after KVproj -> VFt
  unsigned short* Wt4    = (unsigned short*)(ws + 80 * MB);   // WtQ|WtK|WtV|WtF
  float*          biasKV = (float*)(ws + 82 * MB);
  unsigned short* Pbuf   = (unsigned short*)(ws + 83 * MB);
  float*          rowsum = (float*)(ws + 147 * MB);
  const size_t need = 148 * MB;
  if (ws_size < need) return;  // visible failure rather than OOB scribble

  unsigned short* WtQ = Wt4;
  unsigned short* WtKV = Wt4 + 512 * 512;       // [1024][512] = WtK rows then WtV rows
  unsigned short* WtF = Wt4 + 3 * 512 * 512;
  unsigned short* VFn = repb;    // [b][key 2048][e 512] bf16
  unsigned short* VFt = rep1b;   // [b][e 512][key 2048] bf16

  hipMemsetAsync(rowsum, 0, MTOT * 4, stream);
  hipMemcpyAsync(biasKV, Wk_b, 512 * 4, hipMemcpyDeviceToDevice, stream);
  hipMemcpyAsync(biasKV + 512, Wv_b, 512 * 4, hipMemcpyDeviceToDevice, stream);

  cvt_bf16_kernel<<<8192, 256, 0, stream>>>(rep, repb, rep1, rep1b);
  wtrans_kernel<<<dim3(8, 8, 4), 256, 0, stream>>>(Wq_w, Wk_w, Wv_w, FC_w, Wt4);

  // Q = relu(rep Wq + b): [16384,512] x [512,512]^T
  gemm_nt<1, CH, CH, CH, CH, 64><<<dim3(4, 128, 1), 256, 0, stream>>>(
      repb, 0, WtQ, 0, Wq_b, nullptr, 0, Qb, 0);
  // KV = relu(rep1 [Wk|Wv] + b): [16384,512] x [512,1024]^T -> [16384][1024]
  gemm_nt<1, CH, CH, 1024, CH, 64><<<dim3(8, 128, 1), 256, 0, stream>>>(
      rep1b, 0, WtKV, 0, biasKV, nullptr, 0, KVb, 0);

  // VF = V . FC per batch: [2048,512] x [512,512]^T -> [2048][512]   (V = KV cols 512..1023)
  gemm_nt<6, 1024, CH, CH, CH, 64><<<dim3(4, 16, 8), 256, 0, stream>>>(
      KVb + 512, (long)SEQ * 1024, WtF, 0, nullptr, nullptr, 0, VFn, (long)SEQ * CH);

  vtrans_kernel<<<dim3(8, 32, 8), 256, 0, stream>>>(VFn, VFt);

  // P = exp(Q K^T / sqrt(C)) + rowsums: [2048,512] x [2048,512]^T -> [2048,2048]
  gemm_nt<2, CH, 1024, SEQ, CH, 64><<<dim3(16, 16, 8), 256, 0, stream>>>(
      Qb, (long)SEQ * CH, KVb, (long)SEQ * 1024, nullptr, rowsum, SEQ,
      Pbuf, (long)SEQ * SEQ);

  // out = relu(inv[m] * (P . VF) + FC_b): [2048,2048] x VFt[512,2048]^T -> fp32 [2048,512]
  gemm_nt<5, SEQ, SEQ, CH, SEQ, 128><<<dim3(4, 16, 8), 256, 0, stream>>>(
      Pbuf, (long)SEQ * SEQ, VFt, (long)CH * SEQ, FC_b, rowsum, SEQ,
      (void*)out, (long)SEQ * CH);
}

// Round 6
// 296.674 us; speedup vs baseline: 1.0994x; 1.0994x over previous
//
#include <hip/hip_runtime.h>

// Fused attention block: q/k/v = relu(X W + b); A = softmax(qk^T/sqrt(C)); out = relu((A v) FC + b)
// B=8, Lq=Lk=2048, C1=C=512.  bf16 16x16x32 MFMA, fp32 accumulate.
// R5->R6: PVF reverted to BK=64 (m132: BK=128 loses net); VF computed transposed
// natively (A=WtF, B=V rows) deleting vtrans; dispatch graph 13 nodes -> 5 kernels
// (prep = cvt+wtrans+biasKV+rowsum-zero, proj = Q&KV fused).

typedef __attribute__((ext_vector_type(8))) short short8;  // 8 bf16 (4 VGPRs)
typedef __attribute__((ext_vector_type(4))) float f32x4;

#define SEQ 2048
#define CH 512
#define NB 8
#define MTOT (NB * SEQ)   // 16384

// async global->LDS, 16B/lane; LDS dest = wave-uniform base + lane*16 (m104/m108)
#define GLDS16(gp, lp)                                                                  \
  __builtin_amdgcn_global_load_lds((const __attribute__((address_space(1))) void*)(gp), \
                                   (__attribute__((address_space(3))) void*)(lp), 16, 0, 0)

__device__ __forceinline__ unsigned short f2bf(float f) {  // fp32 -> bf16 RNE
  unsigned u = __float_as_uint(f);
  u += 0x7fffu + ((u >> 16) & 1u);
  return (unsigned short)(u >> 16);
}

// ---------------- prep: cvt(rep,rep1) + wtrans x4 + biasKV + rowsum zero ----------------
// blocks [0,8192): cvt; [8192,8448): wtrans (z = (blk-8192)>>6); 8448: biasKV; rest: rowsum=0
__global__ __launch_bounds__(256) void prep_kernel(
    const float* __restrict__ rep, const float* __restrict__ rep1,
    unsigned short* __restrict__ repb, unsigned short* __restrict__ rep1b,
    const float* __restrict__ W0, const float* __restrict__ W1,
    const float* __restrict__ W2, const float* __restrict__ W3,
    unsigned short* __restrict__ Wt,
    const float* __restrict__ Wk_b, const float* __restrict__ Wv_b,
    float* __restrict__ biasKV, float* __restrict__ rowsum) {
  __shared__ __attribute__((aligned(16))) unsigned short tile[64 * 72];
  const int blk = blockIdx.x;
  const int t = threadIdx.x;
  if (blk < 8192) {
    const float* in = (blk < 4096) ? rep : rep1;
    unsigned short* out = (blk < 4096) ? repb : rep1b;
    long i = ((long)(blk & 4095) * 256 + t) * 8;
    float4 a = *(const float4*)(in + i);
    float4 b = *(const float4*)(in + i + 4);
    ushort4 o0, o1;
    o0.x = f2bf(a.x); o0.y = f2bf(a.y); o0.z = f2bf(a.z); o0.w = f2bf(a.w);
    o1.x = f2bf(b.x); o1.y = f2bf(b.y); o1.z = f2bf(b.z); o1.w = f2bf(b.w);
    *(ushort4*)(out + i) = o0;
    *(ushort4*)(out + i + 4) = o1;
  } else if (blk < 8448) {
    const int zz = blk - 8192;
    const int z = zz >> 6;
    const int bx = zz & 7, by = (zz >> 3) & 7;
    const float* W = (z == 0) ? W0 : (z == 1) ? W1 : (z == 2) ? W2 : W3;
    unsigned short* Wtz = Wt + (long)z * 512 * 512;
    const int k0 = by * 64, n0 = bx * 64;
    const int r = t >> 4, cq = (t & 15) * 4;
#pragma unroll
    for (int j = 0; j < 4; ++j) {
      int row = r + 16 * j;  // k index
      float4 v = *(const float4*)&W[(long)(k0 + row) * 512 + n0 + cq];
      tile[row * 72 + cq + 0] = f2bf(v.x);
      tile[row * 72 + cq + 1] = f2bf(v.y);
      tile[row * 72 + cq + 2] = f2bf(v.z);
      tile[row * 72 + cq + 3] = f2bf(v.w);
    }
    __syncthreads();
#pragma unroll
    for (int j = 0; j < 4; ++j) {
      int row = r + 16 * j;  // n index
      ushort4 o;
      o.x = tile[(cq + 0) * 72 + row];
      o.y = tile[(cq + 1) * 72 + row];
      o.z = tile[(cq + 2) * 72 + row];
      o.w = tile[(cq + 3) * 72 + row];
      *(ushort4*)&Wtz[(long)(n0 + row) * 512 + k0 + cq] = o;
    }
  } else if (blk == 8448) {
    biasKV[t] = Wk_b[t];
    biasKV[t + 256] = Wk_b[t + 256];
    biasKV[t + 512] = Wv_b[t];
    biasKV[t + 768] = Wv_b[t + 256];
  } else {
    const int zb = blk - 8449;  // 0..15
    f32x4 z4 = {0.f, 0.f, 0.f, 0.f};
    *(f32x4*)&rowsum[(zb * 256 + t) * 4] = z4;
  }
}

// ---------------- Generic NT GEMM body, 128x128 tile, 4 waves, BK=64 ----------------
// out[m][n] = EPI(sum_k A[m][k] * Bt[n][k])
// EPI 1: relu(acc+bias[n]) -> bf16          (q / kv projections)
// EPI 6: acc               -> bf16          (VFt, computed natively transposed)
// EPI 2: exp2(acc*scale)   -> bf16 P, rowsum[m] += sum_n p   (QK^T)
// EPI 5: relu(acc*inv[m]+bias[n]) -> fp32   (PVF, fused divide+FC-bias+relu)
// Staging: global_load_lds dwordx4, source-XOR swizzle (chunk ^= row&7) -> frag
// ds_read_b128 2-way (free).  Epilogue: single pass via XOR-chunked LDS patch,
// 64B-coalesced stores, one barrier-pair.  A/Bt/rowsum/outp are pre-offset by batch.
template <int EPI, int LDA, int LDB, int LDO, int K, int BK>
__device__ __forceinline__ void gemm_body(const unsigned short* __restrict__ A,
                                          const unsigned short* __restrict__ Bt,
                                          const float* __restrict__ bias,
                                          float* __restrict__ rowsum,
                                          void* __restrict__ outp,
                                          long m0, long n0, unsigned short* smem) {
  unsigned short* Al = smem;
  unsigned short* Bl = smem + 128 * BK;
  const int t = threadIdx.x;
  const int w = t >> 6, l = t & 63;
  const int wr = w >> 1, wc = w & 1;
  const int lr = l & 15, lg = l >> 4;
  constexpr int NC = BK / 8;  // 16B chunks per LDS row
  const int rl = l / NC, cc0 = l % NC;
  unsigned short* la = &Al[32 * w * BK];  // wave-uniform LDS bases
  unsigned short* lb = &Bl[32 * w * BK];
  const int srow = 32 * w + rl;
  const int sxor = (cc0 ^ (rl & (NC - 1))) * 8;
  const unsigned short* ga = A + (m0 + srow) * (long)LDA + sxor;
  const unsigned short* gb = Bt + (n0 + srow) * (long)LDB + sxor;

  f32x4 acc[4][4] = {};
  for (int k0 = 0; k0 < K; k0 += BK) {
#pragma unroll
    for (int j = 0; j < 4; ++j) {
      GLDS16(ga + (long)8 * j * LDA, la + j * 8 * BK);
      GLDS16(gb + (long)8 * j * LDB, lb + j * 8 * BK);
    }
    ga += BK; gb += BK;
    __syncthreads();
#pragma unroll
    for (int h = 0; h < BK / 32; ++h) {
      short8 af[4], bfr[4];
#pragma unroll
      for (int i = 0; i < 4; ++i) {
        const int kc = ((h * 4 + lg) ^ (lr & (NC - 1))) * 8;
        af[i]  = *(short8*)&Al[(64 * wr + 16 * i + lr) * BK + kc];
        bfr[i] = *(short8*)&Bl[(64 * wc + 16 * i + lr) * BK + kc];
      }
#pragma unroll
      for (int mi = 0; mi < 4; ++mi)
#pragma unroll
        for (int ni = 0; ni < 4; ++ni)
          acc[mi][ni] =
              __builtin_amdgcn_mfma_f32_16x16x32_bf16(af[mi], bfr[ni], acc[mi][ni], 0, 0, 0);
    }
    __syncthreads();
  }

  if (EPI == 1 || EPI == 6 || EPI == 2) {
    // bf16 single-pass epilogue via [128][128] XOR-chunked patch (32KB)
    unsigned short* patch = smem;
    float bv[4];
    if (EPI == 1) {
#pragma unroll
      for (int ni = 0; ni < 4; ++ni) bv[ni] = bias[n0 + 64 * wc + 16 * ni + lr];
    }
    float rsum[4][4] = {};
#pragma unroll
    for (int mi = 0; mi < 4; ++mi)
#pragma unroll
      for (int ni = 0; ni < 4; ++ni)
#pragma unroll
        for (int r = 0; r < 4; ++r) {
          const int m = 64 * wr + 16 * mi + 4 * lg + r;
          const int n = 64 * wc + 16 * ni + lr;
          float a = acc[mi][ni][r];
          unsigned short ob;
          if (EPI == 1)      ob = f2bf(fmaxf(a + bv[ni], 0.0f));
          else if (EPI == 6) ob = f2bf(a);
          else {
            float p = exp2f(a * 0.06375872f);  // (1/sqrt(512))*log2(e)
            ob = f2bf(p);
            rsum[mi][r] += __uint_as_float((unsigned)ob << 16);  // sum what PVF will see
          }
          patch[m * 128 + ((n >> 3) ^ (m & 15)) * 8 + (n & 7)] = ob;
        }
    __syncthreads();
    unsigned short* O = (unsigned short*)outp;
    const int q = t & 3;
#pragma unroll
    for (int p = 0; p < 2; ++p) {
      const int m = 64 * p + (t >> 2);
#pragma unroll
      for (int i = 0; i < 4; ++i) {
        const int cc = i * 4 + q;  // 4 consecutive lanes -> 64B line
        short8 x = *(short8*)&patch[m * 128 + ((cc ^ (m & 15)) * 8)];
        *(short8*)&O[(m0 + m) * LDO + n0 + cc * 8] = x;
      }
    }
    if (EPI == 2) {
#pragma unroll
      for (int off = 1; off < 16; off <<= 1)
#pragma unroll
        for (int mi = 0; mi < 4; ++mi)
#pragma unroll
          for (int r = 0; r < 4; ++r) rsum[mi][r] += __shfl_xor(rsum[mi][r], off);
      if (lr == 0) {
#pragma unroll
        for (int mi = 0; mi < 4; ++mi)
#pragma unroll
          for (int r = 0; r < 4; ++r)
            atomicAdd(&rowsum[m0 + 64 * wr + 16 * mi + 4 * lg + r], rsum[mi][r]);
      }
    }
  } else {  // EPI == 5: fp32 out via [128][128] f32 XOR-chunked patch (64KB smem)
    float* patchF = (float*)smem;
    float bv[4];
#pragma unroll
    for (int ni = 0; ni < 4; ++ni) bv[ni] = bias[n0 + 64 * wc + 16 * ni + lr];
    float inv[4][4];
#pragma unroll
    for (int mi = 0; mi < 4; ++mi)
#pragma unroll
      for (int r = 0; r < 4; ++r)
        inv[mi][r] = 1.0f / rowsum[m0 + 64 * wr + 16 * mi + 4 * lg + r];
#pragma unroll
    for (int mi = 0; mi < 4; ++mi)
#pragma unroll
      for (int ni = 0; ni < 4; ++ni)
#pragma unroll
        for (int r = 0; r < 4; ++r) {
          const int m = 64 * wr + 16 * mi + 4 * lg + r;
          const int n = 64 * wc + 16 * ni + lr;
          patchF[m * 128 + ((n >> 2) ^ (m & 31)) * 4 + (n & 3)] =
              fmaxf(acc[mi][ni][r] * inv[mi][r] + bv[ni], 0.0f);
        }
    __syncthreads();
    float* O = (float*)outp;
    const int q = t & 3;
#pragma unroll
    for (int p = 0; p < 2; ++p) {
      const int m = 64 * p + (t >> 2);
#pragma unroll
      for (int i = 0; i < 8; ++i) {
        const int cc = i * 4 + q;  // 4 consecutive lanes -> 64B line
        f32x4 x = *(f32x4*)&patchF[m * 128 + ((cc ^ (m & 31)) * 4)];
        *(f32x4*)&O[(m0 + m) * LDO + n0 + cc * 4] = x;
      }
    }
  }
}

// ---------------- batched GEMM wrapper ----------------
template <int EPI, int LDA, int LDB, int LDO, int K, int BK>
__global__ __launch_bounds__(256) void gemm_nt(const unsigned short* __restrict__ A, long sAb,
                                               const unsigned short* __restrict__ Bt, long sBb,
                                               const float* __restrict__ bias,
                                               float* __restrict__ rowsum, long sRb,
                                               void* __restrict__ outp, long sOb) {
  constexpr int SM = (EPI == 5) ? 32768 : 2 * 128 * BK;  // ushorts; EPI5 needs 64KB patch
  __shared__ __attribute__((aligned(16))) unsigned short smem[SM];
  const int bz = blockIdx.z;
  void* o = (EPI == 5) ? (void*)((float*)outp + (long)bz * sOb)
                       : (void*)((unsigned short*)outp + (long)bz * sOb);
  float* rs = rowsum ? rowsum + (long)bz * sRb : nullptr;
  gemm_body<EPI, LDA, LDB, LDO, K, BK>(A + (long)bz * sAb, Bt + (long)bz * sBb, bias, rs, o,
                                       (long)blockIdx.y * 128, (long)blockIdx.x * 128, smem);
}

// ---------------- fused Q + KV projection (block-uniform template dispatch) ----------------
__global__ __launch_bounds__(256) void proj_kernel(const unsigned short* __restrict__ repb,
                                                   const unsigned short* __restrict__ rep1b,
                                                   const unsigned short* __restrict__ Wt,
                                                   const float* __restrict__ Wq_b,
                                                   const float* __restrict__ biasKV,
                                                   unsigned short* __restrict__ Qb,
                                                   unsigned short* __restrict__ KVb) {
  __shared__ __attribute__((aligned(16))) unsigned short smem[2 * 128 * 64];
  const long m0 = (long)blockIdx.y * 128;
  if (blockIdx.x < 4) {
    gemm_body<1, CH, CH, CH, CH, 64>(repb, Wt, Wq_b, nullptr, Qb, m0,
                                     (long)blockIdx.x * 128, smem);
  } else {
    gemm_body<1, CH, CH, 1024, CH, 64>(rep1b, Wt + 512 * 512, biasKV, nullptr, KVb, m0,
                                       (long)(blockIdx.x - 4) * 128, smem);
  }
}

extern "C" void kernel_launch(void* const* d_in, const int* in_sizes, int n_in,
                              void* d_out, int out_size, void* d_ws, size_t ws_size,
                              hipStream_t stream) {
  const float* rep  = (const float*)d_in[0];
  const float* rep1 = (const float*)d_in[1];
  const float* Wq_w = (const float*)d_in[2];
  const float* Wq_b = (const float*)d_in[3];
  const float* Wk_w = (const float*)d_in[4];
  const float* Wk_b = (const float*)d_in[5];
  const float* Wv_w = (const float*)d_in[6];
  const float* Wv_b = (const float*)d_in[7];
  const float* FC_w = (const float*)d_in[8];
  const float* FC_b = (const float*)d_in[9];
  float* out = (float*)d_out;
  char* ws = (char*)d_ws;

  const size_t MB = 1024 * 1024;
  // layout: Qb 16MB | KVb 32MB | repb 16MB (->VFt) | rep1b 16MB | Wt 2MB | biasKV 4KB |
  //         Pbuf 64MB | rowsum 64KB
  unsigned short* Qb     = (unsigned short*)(ws + 0 * MB);
  unsigned short* KVb    = (unsigned short*)(ws + 16 * MB);
  unsigned short* repb   = (unsigned short*)(ws + 48 * MB);   // dead after proj -> VFt
  unsigned short* rep1b  = (unsigned short*)(ws + 64 * MB);
  unsigned short* Wt4    = (unsigned short*)(ws + 80 * MB);   // WtQ|WtK|WtV|WtF
  float*          biasKV = (float*)(ws + 82 * MB);
  unsigned short* Pbuf   = (unsigned short*)(ws + 83 * MB);
  float*          rowsum = (float*)(ws + 147 * MB);
  const size_t need = 148 * MB;
  if (ws_size < need) return;  // visible failure rather than OOB scribble

  unsigned short* WtQ = Wt4;
  unsigned short* WtF = Wt4 + 3 * 512 * 512;
  unsigned short* VFt = repb;  // [b][e 512][key 2048] bf16

  // prep: cvt + wtrans + biasKV + rowsum-zero (1 dispatch, no API nodes)
  prep_kernel<<<8465, 256, 0, stream>>>(rep, rep1, repb, rep1b, Wq_w, Wk_w, Wv_w, FC_w,
                                        Wt4, Wk_b, Wv_b, biasKV, rowsum);

  // Q = relu(rep Wq + b), KV = relu(rep1 [Wk|Wv] + b) — one dispatch, 1536 blocks
  proj_kernel<<<dim3(12, 128), 256, 0, stream>>>(repb, rep1b, Wt4, Wq_b, biasKV, Qb, KVb);

  // VFt[e][key] = sum_d WtF[e][d] * V[key][d]  (native transposed VF; V = KV cols 512..1023)
  gemm_nt<6, CH, 1024, SEQ, CH, 64><<<dim3(16, 4, 8), 256, 0, stream>>>(
      WtF, 0, KVb + 512, (long)SEQ * 1024, nullptr, nullptr, 0, VFt, (long)CH * SEQ);

  // P = exp(Q K^T / sqrt(C)) + rowsums: [2048,512] x [2048,512]^T -> [2048,2048]
  gemm_nt<2, CH, 1024, SEQ, CH, 64><<<dim3(16, 16, 8), 256, 0, stream>>>(
      Qb, (long)SEQ * CH, KVb, (long)SEQ * 1024, nullptr, rowsum, SEQ,
      Pbuf, (long)SEQ * SEQ);

  // out = relu(inv[m] * (P . VF) + FC_b): [2048,2048] x VFt[512,2048]^T -> fp32 [2048,512]
  gemm_nt<5, SEQ, SEQ, CH, SEQ, 64><<<dim3(4, 16, 8), 256, 0, stream>>>(
      Pbuf, (long)SEQ * SEQ, VFt, (long)CH * SEQ, FC_b, rowsum, SEQ,
      (void*)out, (long)SEQ * CH);
}

// Round 7
// 295.742 us; speedup vs baseline: 1.1029x; 1.0031x over previous
//
#include <hip/hip_runtime.h>

// Fused attention block: q/k/v = relu(X W + b); A = softmax(qk^T/sqrt(C)); out = relu((A v) FC + b)
// B=8, Lq=Lk=2048, C1=C=512.  bf16 16x16x32 MFMA, fp32 accumulate.
// R6->R7: (1) proj reads rep/rep1 fp32 directly (fp32 LDS staging + v_perm truncating
// pack at frag-read) -> cvt prep pass and its 96MB round-trip deleted; (2) VF merged
// into the QK dispatch (qkvf, 2560 blocks); graph is 4 kernels: prep2/proj/qkvf/pvf.

typedef __attribute__((ext_vector_type(8))) short short8;  // 8 bf16 (4 VGPRs)
typedef __attribute__((ext_vector_type(4))) float f32x4;

#define SEQ 2048
#define CH 512
#define NB 8
#define MTOT (NB * SEQ)   // 16384

// async global->LDS, 16B/lane; LDS dest = wave-uniform base + lane*16 (m104/m108)
#define GLDS16(gp, lp)                                                                  \
  __builtin_amdgcn_global_load_lds((const __attribute__((address_space(1))) void*)(gp), \
                                   (__attribute__((address_space(3))) void*)(lp), 16, 0, 0)

__device__ __forceinline__ unsigned short f2bf(float f) {  // fp32 -> bf16 RNE
  unsigned u = __float_as_uint(f);
  u += 0x7fffu + ((u >> 16) & 1u);
  return (unsigned short)(u >> 16);
}

// pack two fp32 -> (bf16(hi)<<16)|bf16(lo) by truncation: one v_perm_b32
__device__ __forceinline__ unsigned pack2bf(float lo, float hi) {
  return __builtin_amdgcn_perm(__float_as_uint(hi), __float_as_uint(lo), 0x07060302u);
}

// ---------------- prep2: wtrans x4 + biasKV + rowsum zero (273 blocks) ----------------
__global__ __launch_bounds__(256) void prep2_kernel(
    const float* __restrict__ W0, const float* __restrict__ W1,
    const float* __restrict__ W2, const float* __restrict__ W3,
    unsigned short* __restrict__ Wt,
    const float* __restrict__ Wk_b, const float* __restrict__ Wv_b,
    float* __restrict__ biasKV, float* __restrict__ rowsum) {
  __shared__ __attribute__((aligned(16))) unsigned short tile[64 * 72];
  const int blk = blockIdx.x;
  const int t = threadIdx.x;
  if (blk < 256) {
    const int z = blk >> 6;
    const int bx = blk & 7, by = (blk >> 3) & 7;
    const float* W = (z == 0) ? W0 : (z == 1) ? W1 : (z == 2) ? W2 : W3;
    unsigned short* Wtz = Wt + (long)z * 512 * 512;
    const int k0 = by * 64, n0 = bx * 64;
    const int r = t >> 4, cq = (t & 15) * 4;
#pragma unroll
    for (int j = 0; j < 4; ++j) {
      int row = r + 16 * j;  // k index
      float4 v = *(const float4*)&W[(long)(k0 + row) * 512 + n0 + cq];
      tile[row * 72 + cq + 0] = f2bf(v.x);
      tile[row * 72 + cq + 1] = f2bf(v.y);
      tile[row * 72 + cq + 2] = f2bf(v.z);
      tile[row * 72 + cq + 3] = f2bf(v.w);
    }
    __syncthreads();
#pragma unroll
    for (int j = 0; j < 4; ++j) {
      int row = r + 16 * j;  // n index
      ushort4 o;
      o.x = tile[(cq + 0) * 72 + row];
      o.y = tile[(cq + 1) * 72 + row];
      o.z = tile[(cq + 2) * 72 + row];
      o.w = tile[(cq + 3) * 72 + row];
      *(ushort4*)&Wtz[(long)(n0 + row) * 512 + k0 + cq] = o;
    }
  } else if (blk == 256) {
    biasKV[t] = Wk_b[t];
    biasKV[t + 256] = Wk_b[t + 256];
    biasKV[t + 512] = Wv_b[t];
    biasKV[t + 768] = Wv_b[t + 256];
  } else {
    const int zb = blk - 257;  // 0..15
    f32x4 z4 = {0.f, 0.f, 0.f, 0.f};
    *(f32x4*)&rowsum[(zb * 256 + t) * 4] = z4;
  }
}

// ---------------- proj body: A fp32 [M][512], Bt bf16 [N][512], 128x128 tile, BK=32 ----
// out = relu(A.Bt^T + bias) -> bf16.  A staged fp32 (16KB) + B bf16 (8KB) via glds,
// XOR source swizzles; A-frag converted fp32->bf16 with v_perm truncation (4/frag).
template <int LDO>
__device__ __forceinline__ void proj_body(const float* __restrict__ A,
                                          const unsigned short* __restrict__ Bt,
                                          const float* __restrict__ bias,
                                          unsigned short* __restrict__ Op,
                                          long m0, long n0, unsigned short* smem) {
  float* Af = (float*)smem;            // [128][32] fp32, 16KB
  unsigned short* Bl = smem + 8192;    // [128][32] bf16, 8KB
  const int t = threadIdx.x;
  const int w = t >> 6, l = t & 63;
  const int wr = w >> 1, wc = w & 1;
  const int lr = l & 15, lg = l >> 4;
  // A staging: 8 lanes/row (4 floats each), src chunk = (l&7)^(l>>3) [= c0 ^ row&7]
  const float* ga = A + (m0 + 32 * w + (l >> 3)) * CH + ((l & 7) ^ (l >> 3)) * 4;
  // B staging: 4 lanes/row (8 bf16 each), src chunk = (l&3)^((l>>3)&3) [= c0 ^ (row>>1)&3]
  const unsigned short* gb =
      Bt + (n0 + 32 * w + (l >> 2)) * CH + (((l & 3) ^ ((l >> 3) & 3)) * 8);
  float* la = Af + 32 * w * 32;
  unsigned short* lb = Bl + 32 * w * 32;

  f32x4 acc[4][4] = {};
  for (int k0 = 0; k0 < CH; k0 += 32) {
#pragma unroll
    for (int j = 0; j < 4; ++j) GLDS16(ga + 8 * j * CH, la + 8 * j * 32);
    GLDS16(gb, lb);
    GLDS16(gb + 16 * CH, lb + 16 * 32);
    ga += 32; gb += 32;
    __syncthreads();
    short8 af[4], bfr[4];
#pragma unroll
    for (int i = 0; i < 4; ++i) {
      const int row = 64 * wr + 16 * i + lr;
      f32x4 a0 = *(f32x4*)&Af[row * 32 + ((2 * lg) ^ (lr & 7)) * 4];
      f32x4 a1 = *(f32x4*)&Af[row * 32 + ((2 * lg + 1) ^ (lr & 7)) * 4];
      union { unsigned u[4]; short8 s; } pk;
      pk.u[0] = pack2bf(a0[0], a0[1]);
      pk.u[1] = pack2bf(a0[2], a0[3]);
      pk.u[2] = pack2bf(a1[0], a1[1]);
      pk.u[3] = pack2bf(a1[2], a1[3]);
      af[i] = pk.s;
      bfr[i] = *(short8*)&Bl[(64 * wc + 16 * i + lr) * 32 + (lg ^ ((lr >> 1) & 3)) * 8];
    }
#pragma unroll
    for (int mi = 0; mi < 4; ++mi)
#pragma unroll
      for (int ni = 0; ni < 4; ++ni)
        acc[mi][ni] =
            __builtin_amdgcn_mfma_f32_16x16x32_bf16(af[mi], bfr[ni], acc[mi][ni], 0, 0, 0);
    __syncthreads();
  }
  // epilogue: relu(+bias) -> bf16 via [128][128] XOR-chunked patch (32KB)
  unsigned short* patch = smem;
  float bv[4];
#pragma unroll
  for (int ni = 0; ni < 4; ++ni) bv[ni] = bias[n0 + 64 * wc + 16 * ni + lr];
#pragma unroll
  for (int mi = 0; mi < 4; ++mi)
#pragma unroll
    for (int ni = 0; ni < 4; ++ni)
#pragma unroll
      for (int r = 0; r < 4; ++r) {
        const int m = 64 * wr + 16 * mi + 4 * lg + r;
        const int n = 64 * wc + 16 * ni + lr;
        patch[m * 128 + ((n >> 3) ^ (m & 15)) * 8 + (n & 7)] =
            f2bf(fmaxf(acc[mi][ni][r] + bv[ni], 0.0f));
      }
  __syncthreads();
  const int q = t & 3;
#pragma unroll
  for (int p = 0; p < 2; ++p) {
    const int m = 64 * p + (t >> 2);
#pragma unroll
    for (int i = 0; i < 4; ++i) {
      const int cc = i * 4 + q;  // 4 consecutive lanes -> 64B line
      short8 x = *(short8*)&patch[m * 128 + ((cc ^ (m & 15)) * 8)];
      *(short8*)&Op[(m0 + m) * LDO + n0 + cc * 8] = x;
    }
  }
}

// Q = relu(rep Wq + b) [x<4]; KV = relu(rep1 [Wk|Wv] + b) [x>=4]
__global__ __launch_bounds__(256) void proj_kernel(const float* __restrict__ rep,
                                                   const float* __restrict__ rep1,
                                                   const unsigned short* __restrict__ Wt,
                                                   const float* __restrict__ Wq_b,
                                                   const float* __restrict__ biasKV,
                                                   unsigned short* __restrict__ Qb,
                                                   unsigned short* __restrict__ KVb) {
  __shared__ __attribute__((aligned(16))) unsigned short smem[16384];  // 32KB
  const long m0 = (long)blockIdx.y * 128;
  if (blockIdx.x < 4)
    proj_body<CH>(rep, Wt, Wq_b, Qb, m0, (long)blockIdx.x * 128, smem);
  else
    proj_body<1024>(rep1, Wt + 512 * 512, biasKV, KVb, m0, (long)(blockIdx.x - 4) * 128, smem);
}

// ---------------- Generic NT GEMM body (bf16 inputs), 128x128 tile, BK=64 ----------------
// EPI 6: acc -> bf16                        (VFt)
// EPI 2: exp2(acc*scale) -> bf16 P, rowsum[m] += sum_n p   (QK^T)
// EPI 5: relu(acc*inv[m]+bias[n]) -> fp32   (PVF)
template <int EPI, int LDA, int LDB, int LDO, int K, int BK>
__device__ __forceinline__ void gemm_body(const unsigned short* __restrict__ A,
                                          const unsigned short* __restrict__ Bt,
                                          const float* __restrict__ bias,
                                          float* __restrict__ rowsum,
                                          void* __restrict__ outp,
                                          long m0, long n0, unsigned short* smem) {
  unsigned short* Al = smem;
  unsigned short* Bl = smem + 128 * BK;
  const int t = threadIdx.x;
  const int w = t >> 6, l = t & 63;
  const int wr = w >> 1, wc = w & 1;
  const int lr = l & 15, lg = l >> 4;
  constexpr int NC = BK / 8;  // 16B chunks per LDS row
  const int rl = l / NC, cc0 = l % NC;
  unsigned short* la = &Al[32 * w * BK];  // wave-uniform LDS bases
  unsigned short* lb = &Bl[32 * w * BK];
  const int srow = 32 * w + rl;
  const int sxor = (cc0 ^ (rl & (NC - 1))) * 8;
  const unsigned short* ga = A + (m0 + srow) * (long)LDA + sxor;
  const unsigned short* gb = Bt + (n0 + srow) * (long)LDB + sxor;

  f32x4 acc[4][4] = {};
  for (int k0 = 0; k0 < K; k0 += BK) {
#pragma unroll
    for (int j = 0; j < 4; ++j) {
      GLDS16(ga + (long)8 * j * LDA, la + j * 8 * BK);
      GLDS16(gb + (long)8 * j * LDB, lb + j * 8 * BK);
    }
    ga += BK; gb += BK;
    __syncthreads();
#pragma unroll
    for (int h = 0; h < BK / 32; ++h) {
      short8 af[4], bfr[4];
#pragma unroll
      for (int i = 0; i < 4; ++i) {
        const int kc = ((h * 4 + lg) ^ (lr & (NC - 1))) * 8;
        af[i]  = *(short8*)&Al[(64 * wr + 16 * i + lr) * BK + kc];
        bfr[i] = *(short8*)&Bl[(64 * wc + 16 * i + lr) * BK + kc];
      }
#pragma unroll
      for (int mi = 0; mi < 4; ++mi)
#pragma unroll
        for (int ni = 0; ni < 4; ++ni)
          acc[mi][ni] =
              __builtin_amdgcn_mfma_f32_16x16x32_bf16(af[mi], bfr[ni], acc[mi][ni], 0, 0, 0);
    }
    __syncthreads();
  }

  if (EPI == 6 || EPI == 2) {
    // bf16 single-pass epilogue via [128][128] XOR-chunked patch (32KB)
    unsigned short* patch = smem;
    float rsum[4][4] = {};
#pragma unroll
    for (int mi = 0; mi < 4; ++mi)
#pragma unroll
      for (int ni = 0; ni < 4; ++ni)
#pragma unroll
        for (int r = 0; r < 4; ++r) {
          const int m = 64 * wr + 16 * mi + 4 * lg + r;
          const int n = 64 * wc + 16 * ni + lr;
          float a = acc[mi][ni][r];
          unsigned short ob;
          if (EPI == 6) ob = f2bf(a);
          else {
            float p = exp2f(a * 0.06375872f);  // (1/sqrt(512))*log2(e)
            ob = f2bf(p);
            rsum[mi][r] += __uint_as_float((unsigned)ob << 16);  // sum what PVF will see
          }
          patch[m * 128 + ((n >> 3) ^ (m & 15)) * 8 + (n & 7)] = ob;
        }
    __syncthreads();
    unsigned short* O = (unsigned short*)outp;
    const int q = t & 3;
#pragma unroll
    for (int p = 0; p < 2; ++p) {
      const int m = 64 * p + (t >> 2);
#pragma unroll
      for (int i = 0; i < 4; ++i) {
        const int cc = i * 4 + q;  // 4 consecutive lanes -> 64B line
        short8 x = *(short8*)&patch[m * 128 + ((cc ^ (m & 15)) * 8)];
        *(short8*)&O[(m0 + m) * LDO + n0 + cc * 8] = x;
      }
    }
    if (EPI == 2) {
#pragma unroll
      for (int off = 1; off < 16; off <<= 1)
#pragma unroll
        for (int mi = 0; mi < 4; ++mi)
#pragma unroll
          for (int r = 0; r < 4; ++r) rsum[mi][r] += __shfl_xor(rsum[mi][r], off);
      if (lr == 0) {
#pragma unroll
        for (int mi = 0; mi < 4; ++mi)
#pragma unroll
          for (int r = 0; r < 4; ++r)
            atomicAdd(&rowsum[m0 + 64 * wr + 16 * mi + 4 * lg + r], rsum[mi][r]);
      }
    }
  } else {  // EPI == 5: fp32 out via [128][128] f32 XOR-chunked patch (64KB smem)
    float* patchF = (float*)smem;
    float bv[4];
#pragma unroll
    for (int ni = 0; ni < 4; ++ni) bv[ni] = bias[n0 + 64 * wc + 16 * ni + lr];
    float inv[4][4];
#pragma unroll
    for (int mi = 0; mi < 4; ++mi)
#pragma unroll
      for (int r = 0; r < 4; ++r)
        inv[mi][r] = 1.0f / rowsum[m0 + 64 * wr + 16 * mi + 4 * lg + r];
#pragma unroll
    for (int mi = 0; mi < 4; ++mi)
#pragma unroll
      for (int ni = 0; ni < 4; ++ni)
#pragma unroll
        for (int r = 0; r < 4; ++r) {
          const int m = 64 * wr + 16 * mi + 4 * lg + r;
          const int n = 64 * wc + 16 * ni + lr;
          patchF[m * 128 + ((n >> 2) ^ (m & 31)) * 4 + (n & 3)] =
              fmaxf(acc[mi][ni][r] * inv[mi][r] + bv[ni], 0.0f);
        }
    __syncthreads();
    float* O = (float*)outp;
    const int q = t & 3;
#pragma unroll
    for (int p = 0; p < 2; ++p) {
      const int m = 64 * p + (t >> 2);
#pragma unroll
      for (int i = 0; i < 8; ++i) {
        const int cc = i * 4 + q;  // 4 consecutive lanes -> 64B line
        f32x4 x = *(f32x4*)&patchF[m * 128 + ((cc ^ (m & 31)) * 4)];
        *(f32x4*)&O[(m0 + m) * LDO + n0 + cc * 4] = x;
      }
    }
  }
}

// ---------------- qkvf: P=exp(QK^T/s)+rowsum [y<16] and VFt=WtF.V^T [y>=16] ----------------
__global__ __launch_bounds__(256) void qkvf_kernel(const unsigned short* __restrict__ Qb,
                                                   const unsigned short* __restrict__ KVb,
                                                   const unsigned short* __restrict__ WtF,
                                                   float* __restrict__ rowsum,
                                                   unsigned short* __restrict__ Pbuf,
                                                   unsigned short* __restrict__ VFt) {
  __shared__ __attribute__((aligned(16))) unsigned short smem[2 * 128 * 64];
  const int bz = blockIdx.z;
  if (blockIdx.y < 16) {
    gemm_body<2, CH, 1024, SEQ, CH, 64>(
        Qb + (long)bz * SEQ * CH, KVb + (long)bz * SEQ * 1024, nullptr,
        rowsum + (long)bz * SEQ, Pbuf + (long)bz * SEQ * SEQ,
        (long)blockIdx.y * 128, (long)blockIdx.x * 128, smem);
  } else {
    gemm_body<6, CH, 1024, SEQ, CH, 64>(
        WtF, KVb + 512 + (long)bz * SEQ * 1024, nullptr, nullptr,
        VFt + (long)bz * CH * SEQ,
        (long)(blockIdx.y - 16) * 128, (long)blockIdx.x * 128, smem);
  }
}

// ---------------- pvf: out = relu(inv[m]*(P.VFt^T) + FC_b) -> fp32 ----------------
__global__ __launch_bounds__(256) void pvf_kernel(const unsigned short* __restrict__ Pbuf,
                                                  const unsigned short* __restrict__ VFt,
                                                  const float* __restrict__ FC_b,
                                                  float* __restrict__ rowsum,
                                                  float* __restrict__ out) {
  __shared__ __attribute__((aligned(16))) unsigned short smem[32768];  // 64KB (fp32 patch)
  const int bz = blockIdx.z;
  gemm_body<5, SEQ, SEQ, CH, SEQ, 64>(
      Pbuf + (long)bz * SEQ * SEQ, VFt + (long)bz * CH * SEQ, FC_b,
      rowsum + (long)bz * SEQ, out + (long)bz * SEQ * CH,
      (long)blockIdx.y * 128, (long)blockIdx.x * 128, smem);
}

extern "C" void kernel_launch(void* const* d_in, const int* in_sizes, int n_in,
                              void* d_out, int out_size, void* d_ws, size_t ws_size,
                              hipStream_t stream) {
  const float* rep  = (const float*)d_in[0];
  const float* rep1 = (const float*)d_in[1];
  const float* Wq_w = (const float*)d_in[2];
  const float* Wq_b = (const float*)d_in[3];
  const float* Wk_w = (const float*)d_in[4];
  const float* Wk_b = (const float*)d_in[5];
  const float* Wv_w = (const float*)d_in[6];
  const float* Wv_b = (const float*)d_in[7];
  const float* FC_w = (const float*)d_in[8];
  const float* FC_b = (const float*)d_in[9];
  float* out = (float*)d_out;
  char* ws = (char*)d_ws;

  const size_t MB = 1024 * 1024;
  // layout: Qb 16MB | KVb 32MB | VFt 16MB | Wt 2MB | biasKV 4KB(+pad) | Pbuf 64MB | rowsum 64KB
  unsigned short* Qb     = (unsigned short*)(ws + 0 * MB);
  unsigned short* KVb    = (unsigned short*)(ws + 16 * MB);
  unsigned short* VFt    = (unsigned short*)(ws + 48 * MB);  // [b][e 512][key 2048]
  unsigned short* Wt4    = (unsigned short*)(ws + 64 * MB);  // WtQ|WtK|WtV|WtF
  float*          biasKV = (float*)(ws + 66 * MB);
  unsigned short* Pbuf   = (unsigned short*)(ws + 67 * MB);
  float*          rowsum = (float*)(ws + 131 * MB);
  const size_t need = 132 * MB;
  if (ws_size < need) return;  // visible failure rather than OOB scribble

  unsigned short* WtF = Wt4 + 3 * 512 * 512;

  // wtrans + biasKV + rowsum-zero (tiny)
  prep2_kernel<<<273, 256, 0, stream>>>(Wq_w, Wk_w, Wv_w, FC_w, Wt4, Wk_b, Wv_b,
                                        biasKV, rowsum);

  // Q/KV projections straight from fp32 activations
  proj_kernel<<<dim3(12, 128), 256, 0, stream>>>(rep, rep1, Wt4, Wq_b, biasKV, Qb, KVb);

  // P = exp(QK^T/sqrt(C)) + rowsums  ||  VFt = (V.FC)^T
  qkvf_kernel<<<dim3(16, 20, 8), 256, 0, stream>>>(Qb, KVb, WtF, rowsum, Pbuf, VFt);

  // out = relu(inv[m] * (P.VF) + FC_b)
  pvf_kernel<<<dim3(4, 16, 8), 256, 0, stream>>>(Pbuf, VFt, FC_b, rowsum, out);
}